// Round 1
// baseline (616.679 us; speedup 1.0000x reference)
//
#include <hip/hip_runtime.h>

// VarDecoder: N=256, CAT_IN=1024, H=512, V=32000, T=8
// Round 3: mega-fusion. 3 launches:
//   1) cvt_all   — all fp32->bf16 conversions (incl. W_out) + barrier zero
//   2) decoder_core — merge GEMM + x_proj + 8 LSTM steps in ONE kernel:
//        - Whh slice persistent in 128KB LDS (bank-swizzled, rule-21 pattern)
//        - xp (x_proj+biases) and c kept in registers for all 8 steps
//        - per-n-group device barrier (16 blocks/group, atomic counter)
//   3) logits GEMM (unchanged m97-style 128x128 bf16 MFMA, MODE 2 scatter)

#define GLOBAL_AS __attribute__((address_space(1)))
#define LDS_AS __attribute__((address_space(3)))

typedef __attribute__((ext_vector_type(8))) short short8;   // 8 x bf16
typedef __attribute__((ext_vector_type(4))) float f32x4;    // MFMA accumulator

constexpr int N_  = 256;
constexpr int CIN = 1024;
constexpr int H_  = 512;
constexpr int G4  = 2048;   // 4*H
constexpr int V_  = 32000;
constexpr int T_  = 8;

__device__ inline short f2bf(float f) {   // fp32 -> bf16 RNE
  union { float f; unsigned u; } v; v.f = f;
  unsigned r = v.u + 0x7fffu + ((v.u >> 16) & 1u);
  return (short)(r >> 16);
}

__device__ inline void async16(const void* g, void* l) {
  __builtin_amdgcn_global_load_lds((const GLOBAL_AS unsigned*)g,
                                   (LDS_AS unsigned*)l, 16, 0, 0);
}

__device__ inline float sigm(float x) { return 1.0f / (1.0f + __expf(-x)); }
__device__ inline float tanh_fast(float x) {
  x = fminf(15.0f, fmaxf(-15.0f, x));
  float e = __expf(2.0f * x);
  return (e - 1.0f) / (e + 1.0f);
}

// per-n-group device barrier: monotone counter, 16 blocks/group, all resident
// (128 blocks total on 256 CUs). __threadfence() = agent fence (wbL2/inv) for
// cross-XCD visibility of normal stores.
__device__ inline void gbar(unsigned* cnt) {
  __threadfence();
  __syncthreads();
  if (threadIdx.x == 0) {
    unsigned v = atomicAdd(cnt, 1u);
    unsigned tgt = (v & ~15u) + 16u;     // end of this phase (16 arrivals)
    while (atomicAdd(cnt, 0u) < tgt) __builtin_amdgcn_s_sleep(2);
  }
  __syncthreads();
  __threadfence();
}

// ---------------- fp32 -> bf16 for all 5 arrays + barrier zeroing -------------
__global__ __launch_bounds__(256) void cvt_all(
    const float* __restrict__ s0, short* __restrict__ d0, int c0,  // W_out
    const float* __restrict__ s1, short* __restrict__ d1, int c1,  // context
    const float* __restrict__ s2, short* __restrict__ d2, int c2,  // W_merge
    const float* __restrict__ s3, short* __restrict__ d3, int c3,  // W_ih
    const float* __restrict__ s4, short* __restrict__ d4, int c4,  // W_hh
    unsigned* __restrict__ bar) {
  int i = blockIdx.x * 256 + threadIdx.x;
  if (blockIdx.x == 0) bar[threadIdx.x] = 0u;   // 256 counters zeroed each run
  const float* s; short* d; int k;
  if (i < c0)                          { s = s0; d = d0; k = i; }
  else if (i < c0 + c1)                { s = s1; d = d1; k = i - c0; }
  else if (i < c0 + c1 + c2)           { s = s2; d = d2; k = i - c0 - c1; }
  else if (i < c0 + c1 + c2 + c3)      { s = s3; d = d3; k = i - c0 - c1 - c2; }
  else if (i < c0 + c1 + c2 + c3 + c4) { s = s4; d = d4; k = i - c0 - c1 - c2 - c3; }
  else return;
  float4 v = ((const float4*)s)[k];
  short4 o;
  o.x = f2bf(v.x); o.y = f2bf(v.y); o.z = f2bf(v.z); o.w = f2bf(v.w);
  ((short4*)d)[k] = o;
}

// ---------------- fused decoder core -----------------------------------------
// grid (16, 8): j0 = x*32 (H tiles), n0 = y*32 (N tiles). 256 thr = 4 waves.
// Wave w owns gate w. LDS: WhhL 128KB persistent + 32KB scratch = 160KB.
__global__ __launch_bounds__(256, 1) void decoder_core(
    const short* __restrict__ Ctxin,   // [N][CIN] bf16
    const short* __restrict__ Wmrg,    // [H][CIN] bf16
    const float* __restrict__ bmrg,    // [H]
    const short* __restrict__ Wih,     // [G4][H] bf16
    const short* __restrict__ Whh,     // [G4][H] bf16
    const float* __restrict__ bih,
    const float* __restrict__ bhh,
    short* __restrict__ ctx,           // [N][H] bf16 scratch out
    short* __restrict__ Hall,          // [T][N][H] bf16 out
    unsigned* __restrict__ bar)
{
  __shared__ alignas(16) short WhhL[128 * H_];   // 128 KB, swizzled content
  __shared__ alignas(16) char scratch[32768];    // union: merge bufs / G / As+Bs / HL

  const int tid   = threadIdx.x;
  const int lane  = tid & 63;
  const int w     = tid >> 6;            // gate 0..3 (i,f,g,o)
  const int rlane = lane & 15;
  const int klane = (lane >> 4) * 8;     // shorts
  const int qrow  = (lane >> 4) * 4;     // C-layout row base
  const int j0    = blockIdx.x * 32;
  const int n0    = blockIdx.y * 32;
  unsigned* mybar = bar + blockIdx.y * 32;   // 128B-spaced counter per n-group
  const int swz   = (rlane & 7) << 4;        // read-side XOR for 1024B-stride rows

  // ---- phase 0: issue persistent Whh slice load (swizzled placement) ----
  // LDS row r = gate*32 + jj  <->  global row (r>>5)*H_ + j0 + (r&31).
  // Linear LDS dest (gload_lds constraint); source k pre-swizzled so that
  // read addr (row*1024 + 2k) ^ ((row&7)<<4) returns logical (row,k). [rule 21]
#pragma unroll
  for (int i = 0; i < 32; ++i) {
    int c = i * 256 + tid;                  // 16B chunk id, 64 chunks/row
    int r = c >> 6, cq = c & 63;
    int ks = ((cq << 4) ^ ((r & 7) << 4)) >> 1;   // source short offset in row
    async16(Whh + (size_t)((r >> 5) * H_ + j0 + (r & 31)) * H_ + ks,
            &WhhL[(size_t)(i * 256 + (tid & ~63)) * 8]);
  }

  // ---- phase 1: merge GEMM  ctx[n0:+32][j0:+32] = context @ Wmrg^T + b ----
  // per-wave K-quarter (kb = w*256), partials reduced through LDS.
  {
    short* Aw = (short*)scratch + w * 2048;   // [32][32] bf16 per wave
    short* Bw = Aw + 1024;
    f32x4 m00 = {0,0,0,0}, m01 = {0,0,0,0}, m10 = {0,0,0,0}, m11 = {0,0,0,0};
    const int kb = w * 256;
    for (int i = 0; i < 8; ++i) {
      int kc = kb + i * 32;
#pragma unroll
      for (int p = 0; p < 2; ++p) {
        int cA = p * 64 + lane;
        async16(Ctxin + (size_t)(n0 + (cA >> 2)) * CIN + kc + (cA & 3) * 8,
                Aw + p * 512);
        async16(Wmrg + (size_t)(j0 + (cA >> 2)) * CIN + kc + (cA & 3) * 8,
                Bw + p * 512);
      }
      asm volatile("s_waitcnt vmcnt(0)" ::: "memory");   // per-wave drain
      __builtin_amdgcn_sched_barrier(0);
      short8 ma0 = *(const short8*)&Aw[rlane * 32 + klane];
      short8 ma1 = *(const short8*)&Aw[(16 + rlane) * 32 + klane];
      short8 mb0 = *(const short8*)&Bw[rlane * 32 + klane];
      short8 mb1 = *(const short8*)&Bw[(16 + rlane) * 32 + klane];
      m00 = __builtin_amdgcn_mfma_f32_16x16x32_bf16(ma0, mb0, m00, 0, 0, 0);
      m01 = __builtin_amdgcn_mfma_f32_16x16x32_bf16(ma0, mb1, m01, 0, 0, 0);
      m10 = __builtin_amdgcn_mfma_f32_16x16x32_bf16(ma1, mb0, m10, 0, 0, 0);
      m11 = __builtin_amdgcn_mfma_f32_16x16x32_bf16(ma1, mb1, m11, 0, 0, 0);
      asm volatile("s_waitcnt lgkmcnt(0)" ::: "memory"); // WAR: reads landed
      __builtin_amdgcn_sched_barrier(0);
    }
    __syncthreads();
    float* G = (float*)scratch;           // [4][32][32] partials overlay
#pragma unroll
    for (int r = 0; r < 4; ++r) {
      G[(w * 32 + qrow + r) * 32 + rlane]           = m00[r];
      G[(w * 32 + qrow + r) * 32 + 16 + rlane]      = m01[r];
      G[(w * 32 + 16 + qrow + r) * 32 + rlane]      = m10[r];
      G[(w * 32 + 16 + qrow + r) * 32 + 16 + rlane] = m11[r];
    }
    __syncthreads();
    int nn = tid >> 3, jq = tid & 7;
    const float4* Gv = (const float4*)scratch;
    float4 p0 = Gv[(0 * 32 + nn) * 8 + jq];
    float4 p1 = Gv[(1 * 32 + nn) * 8 + jq];
    float4 p2 = Gv[(2 * 32 + nn) * 8 + jq];
    float4 p3 = Gv[(3 * 32 + nn) * 8 + jq];
    int jb = j0 + jq * 4;
    short4 o;
    o.x = f2bf(p0.x + p1.x + p2.x + p3.x + bmrg[jb + 0]);
    o.y = f2bf(p0.y + p1.y + p2.y + p3.y + bmrg[jb + 1]);
    o.z = f2bf(p0.z + p1.z + p2.z + p3.z + bmrg[jb + 2]);
    o.w = f2bf(p0.w + p1.w + p2.w + p3.w + bmrg[jb + 3]);
    *(short4*)&ctx[(size_t)(n0 + nn) * H_ + jb] = o;
  }
  gbar(mybar);   // ctx rows n0:+32 complete across the 16 j-blocks

  // ---- phase 2: x_proj in registers  xp = ctx @ Wih^T + b_ih + b_hh ----
  f32x4 x00, x01, x10, x11;
  {
    int ng0 = w * H_ + j0 + rlane, ng1 = ng0 + 16;
    float bc0 = bih[ng0] + bhh[ng0];
    float bc1 = bih[ng1] + bhh[ng1];
    x00 = (f32x4){bc0, bc0, bc0, bc0};  x01 = (f32x4){bc1, bc1, bc1, bc1};
    x10 = x00;                          x11 = x01;
    short* As = (short*)scratch;            // [32][32]  (2 KB)
    short* Bs = (short*)(scratch + 4096);   // [128][32] (8 KB)
    for (int kc = 0; kc < H_; kc += 32) {
      if (w < 2)
        async16(ctx + (size_t)(n0 + (tid >> 2)) * H_ + kc + (tid & 3) * 8,
                &As[(tid & ~63) * 8]);
#pragma unroll
      for (int p = 0; p < 2; ++p) {
        int idx = p * 256 + tid;
        int br = idx >> 2, q = idx & 3;
        async16(Wih + (size_t)((br >> 5) * H_ + j0 + (br & 31)) * H_ + q * 8 + kc,
                &Bs[(idx & ~63) * 8]);
      }
      __syncthreads();
      short8 xa0 = *(const short8*)&As[rlane * 32 + klane];
      short8 xa1 = *(const short8*)&As[(16 + rlane) * 32 + klane];
      short8 xb0 = *(const short8*)&Bs[(w * 32 + rlane) * 32 + klane];
      short8 xb1 = *(const short8*)&Bs[(w * 32 + 16 + rlane) * 32 + klane];
      x00 = __builtin_amdgcn_mfma_f32_16x16x32_bf16(xa0, xb0, x00, 0, 0, 0);
      x01 = __builtin_amdgcn_mfma_f32_16x16x32_bf16(xa0, xb1, x01, 0, 0, 0);
      x10 = __builtin_amdgcn_mfma_f32_16x16x32_bf16(xa1, xb0, x10, 0, 0, 0);
      x11 = __builtin_amdgcn_mfma_f32_16x16x32_bf16(xa1, xb1, x11, 0, 0, 0);
      __syncthreads();
    }
  }

  // ---- phase 3: 8 LSTM steps; c in registers; Whh from persistent LDS ----
  float creg[4] = {0.f, 0.f, 0.f, 0.f};
  const int ne = tid >> 3, jq = tid & 7;
  const int r_b0 = w * 32 + rlane, r_b1 = r_b0 + 16;
  const char* WLb = (const char*)WhhL;
  const char* HLb = (const char*)scratch;     // [32][512] swizzled Hprev tile

  for (int t = 0; t < T_; ++t) {
    f32x4 a00 = x00, a01 = x01, a10 = x10, a11 = x11;
    if (t > 0) {
      const short* Hp = Hall + (size_t)(t - 1) * N_ * H_;
#pragma unroll
      for (int i = 0; i < 8; ++i) {           // 2048 chunks, pre-swizzled source
        int c = i * 256 + tid;
        int r = c >> 6, cq = c & 63;
        int ks = ((cq << 4) ^ ((r & 7) << 4)) >> 1;
        async16(Hp + (size_t)(n0 + r) * H_ + ks,
                (void*)(HLb + (size_t)(i * 256 + (tid & ~63)) * 16));
      }
      __syncthreads();                        // vmcnt(0) + barrier: HL valid
#pragma unroll
      for (int kc = 0; kc < H_; kc += 32) {   // barrier-free LDS->MFMA K-loop
        int ko = (kc + klane) * 2;
        short8 a0 = *(const short8*)(HLb + ((rlane * 1024 + ko) ^ swz));
        short8 a1 = *(const short8*)(HLb + (((16 + rlane) * 1024 + ko) ^ swz));
        short8 b0 = *(const short8*)(WLb + ((r_b0 * 1024 + ko) ^ swz));
        short8 b1 = *(const short8*)(WLb + ((r_b1 * 1024 + ko) ^ swz));
        a00 = __builtin_amdgcn_mfma_f32_16x16x32_bf16(a0, b0, a00, 0, 0, 0);
        a01 = __builtin_amdgcn_mfma_f32_16x16x32_bf16(a0, b1, a01, 0, 0, 0);
        a10 = __builtin_amdgcn_mfma_f32_16x16x32_bf16(a1, b0, a10, 0, 0, 0);
        a11 = __builtin_amdgcn_mfma_f32_16x16x32_bf16(a1, b1, a11, 0, 0, 0);
      }
      __syncthreads();                        // HL reads done before G overlay
    }
    // gate exchange via LDS: G[gate][n][j]
    float* G = (float*)scratch;
#pragma unroll
    for (int r = 0; r < 4; ++r) {
      G[(w * 32 + qrow + r) * 32 + rlane]           = a00[r];
      G[(w * 32 + qrow + r) * 32 + 16 + rlane]      = a01[r];
      G[(w * 32 + 16 + qrow + r) * 32 + rlane]      = a10[r];
      G[(w * 32 + 16 + qrow + r) * 32 + 16 + rlane] = a11[r];
    }
    __syncthreads();
    float4 gi = ((const float4*)G)[(0 * 32 + ne) * 8 + jq];
    float4 gf = ((const float4*)G)[(1 * 32 + ne) * 8 + jq];
    float4 gg = ((const float4*)G)[(2 * 32 + ne) * 8 + jq];
    float4 go = ((const float4*)G)[(3 * 32 + ne) * 8 + jq];
    float pi[4] = {gi.x, gi.y, gi.z, gi.w};
    float pf[4] = {gf.x, gf.y, gf.z, gf.w};
    float pg[4] = {gg.x, gg.y, gg.z, gg.w};
    float po[4] = {go.x, go.y, go.z, go.w};
    short hv[4];
#pragma unroll
    for (int e = 0; e < 4; ++e) {
      float ii = sigm(pi[e]), ff = sigm(pf[e]);
      float g2 = tanh_fast(pg[e]), oo = sigm(po[e]);
      float cv = ff * creg[e] + ii * g2;     // t=0: creg=0 == h0,c0=0
      creg[e] = cv;
      hv[e] = f2bf(oo * tanh_fast(cv));
    }
    short4 h4; h4.x = hv[0]; h4.y = hv[1]; h4.z = hv[2]; h4.w = hv[3];
    *(short4*)&Hall[(size_t)t * N_ * H_ + (size_t)(n0 + ne) * H_ + j0 + jq * 4] = h4;
    if (t < T_ - 1) gbar(mybar);             // Hall[t] visible to n-group
  }
}

// ------------- bf16 MFMA GEMM-BT: C[M,N] = A[M,K] @ B[N,K]^T -----------------
// MODE 2: C fp32, row m = t*256+n remapped to out[n][t][v], + bias1.
template<int BM, int BN, int MODE>
__global__ __launch_bounds__(256) void gemm_bf16_bt(
    const short* __restrict__ A, const short* __restrict__ B,
    const float* __restrict__ bias1, const float* __restrict__ bias2,
    void* __restrict__ Cv, int M, int N, int K)
{
  constexpr int RT = BM / 32;
  constexpr int CT = BN / 32;
  __shared__ short As[BM * 32];
  __shared__ short Bs[BN * 32];

  const int tid = threadIdx.x;
  const int lane = tid & 63;
  const int w = tid >> 6;
  const int wr = w >> 1, wc = w & 1;
  const int m0 = blockIdx.y * BM;
  const int n0 = blockIdx.x * BN;
  const int rlane = lane & 15;
  const int klane = (lane >> 4) * 8;

  f32x4 acc[RT][CT] = {};

  for (int kc = 0; kc < K; kc += 32) {
#pragma unroll
    for (int it = 0; it < (BM * 4) / 256; ++it) {
      int idx = it * 256 + tid;
      const short* g = A + (size_t)(m0 + (idx >> 2)) * K + kc + (idx & 3) * 8;
      async16(g, &As[(size_t)(it * 256 + (tid & ~63)) * 8]);
    }
#pragma unroll
    for (int it = 0; it < (BN * 4) / 256; ++it) {
      int idx = it * 256 + tid;
      const short* g = B + (size_t)(n0 + (idx >> 2)) * K + kc + (idx & 3) * 8;
      async16(g, &Bs[(size_t)(it * 256 + (tid & ~63)) * 8]);
    }
    __syncthreads();

    short8 af[RT], bf[CT];
#pragma unroll
    for (int rt = 0; rt < RT; ++rt)
      af[rt] = *(const short8*)&As[(wr * (RT * 16) + rt * 16 + rlane) * 32 + klane];
#pragma unroll
    for (int ct = 0; ct < CT; ++ct)
      bf[ct] = *(const short8*)&Bs[(wc * (CT * 16) + ct * 16 + rlane) * 32 + klane];
#pragma unroll
    for (int rt = 0; rt < RT; ++rt)
#pragma unroll
      for (int ct = 0; ct < CT; ++ct)
        acc[rt][ct] = __builtin_amdgcn_mfma_f32_16x16x32_bf16(af[rt], bf[ct],
                                                              acc[rt][ct], 0, 0, 0);
    __syncthreads();
  }

  // C/D layout: col = lane&15, row = (lane>>4)*4 + reg
#pragma unroll
  for (int ct = 0; ct < CT; ++ct) {
    int ng = n0 + wc * (CT * 16) + ct * 16 + rlane;
    float bv = (bias1 ? bias1[ng] : 0.0f) + (bias2 ? bias2[ng] : 0.0f);
#pragma unroll
    for (int rt = 0; rt < RT; ++rt)
#pragma unroll
      for (int r = 0; r < 4; ++r) {
        int mg = m0 + wr * (RT * 16) + rt * 16 + (lane >> 4) * 4 + r;
        float v = acc[rt][ct][r] + bv;
        if (MODE == 2) {
          int t = mg >> 8, nb = mg & 255;
          ((float*)Cv)[(size_t)nb * (T_ * V_) + (size_t)t * V_ + ng] = v;
        } else if (MODE == 1) {
          ((short*)Cv)[(size_t)mg * N + ng] = f2bf(v);
        } else {
          ((float*)Cv)[(size_t)mg * N + ng] = v;
        }
      }
  }
}

extern "C" void kernel_launch(void* const* d_in, const int* in_sizes, int n_in,
                              void* d_out, int out_size, void* d_ws, size_t ws_size,
                              hipStream_t stream)
{
  (void)in_sizes; (void)n_in; (void)out_size; (void)ws_size;
  const float* context = (const float*)d_in[0];
  const float* W_merge = (const float*)d_in[1];
  const float* b_merge = (const float*)d_in[2];
  const float* W_ih    = (const float*)d_in[3];
  const float* W_hh    = (const float*)d_in[4];
  const float* b_ih    = (const float*)d_in[5];
  const float* b_hh    = (const float*)d_in[6];
  const float* W_out   = (const float*)d_in[7];
  const float* b_out   = (const float*)d_in[8];
  float* out = (float*)d_out;

  // workspace layout (~40 MB)
  char* p = (char*)d_ws;
  short* Wout_b  = (short*)p;  p += (size_t)V_ * H_ * 2;       // 32.77 MB
  short* Whh_b   = (short*)p;  p += (size_t)G4 * H_ * 2;       // 2 MB
  short* Wih_b   = (short*)p;  p += (size_t)G4 * H_ * 2;       // 2 MB
  short* Wmrg_b  = (short*)p;  p += (size_t)H_ * CIN * 2;      // 1 MB
  short* Ctxin_b = (short*)p;  p += (size_t)N_ * CIN * 2;      // 0.5 MB
  short* Ctx_b   = (short*)p;  p += (size_t)N_ * H_ * 2;       // 0.25 MB
  short* Hall    = (short*)p;  p += (size_t)T_ * N_ * H_ * 2;  // 2 MB [t][n][k]
  unsigned* bar  = (unsigned*)p; p += 256 * 4;                 // 1 KB barriers

  // 1) all conversions + barrier zeroing (one launch)
  {
    int c0 = V_ * H_ / 4, c1 = N_ * CIN / 4, c2 = H_ * CIN / 4;
    int c3 = G4 * H_ / 4, c4 = G4 * H_ / 4;
    int tot = c0 + c1 + c2 + c3 + c4;
    cvt_all<<<(tot + 255) / 256, 256, 0, stream>>>(
        W_out, Wout_b, c0, context, Ctxin_b, c1, W_merge, Wmrg_b, c2,
        W_ih, Wih_b, c3, W_hh, Whh_b, c4, bar);
  }

  // 2) fused merge + x_proj + 8 LSTM steps
  decoder_core<<<dim3(H_ / 32, N_ / 32), 256, 0, stream>>>(
      Ctxin_b, Wmrg_b, b_merge, Wih_b, Whh_b, b_ih, b_hh, Ctx_b, Hall, bar);

  // 3) logits: [2048 x 32000] = Hall @ W_out^T + b_out -> out[N,T,V]
  gemm_bf16_bt<128, 128, 2><<<dim3(V_ / 128, (T_ * N_) / 128), 256, 0, stream>>>(
      Hall, Wout_b, b_out, nullptr, out, T_ * N_, V_, H_);
}

// Round 2
// 498.020 us; speedup vs baseline: 1.2383x; 1.2383x over previous
//
#include <hip/hip_runtime.h>

// VarDecoder: N=256, CAT_IN=1024, H=512, V=32000, T=8
// Round 4: mega-fusion v2 — fence-free device barriers.
//   Cross-block data (ctx, Hall[t]) moves via RELAXED AGENT-scope atomic
//   stores/loads (sc1 write-through / MALL reads) so group barriers need only
//   vmcnt(0) (emitted by __syncthreads) + a relaxed atomic counter — no
//   __threadfence / buffer_wbl2. Whh persistent-LDS load reordered to after
//   x_proj (first use is t=1). Phase-2 ctx tile lives in LDS (loaded once).
// 3 launches: cvt_all, decoder_core, logits GEMM.

#define GLOBAL_AS __attribute__((address_space(1)))
#define LDS_AS __attribute__((address_space(3)))

typedef __attribute__((ext_vector_type(8))) short short8;   // 8 x bf16
typedef __attribute__((ext_vector_type(4))) float f32x4;    // MFMA accumulator
typedef unsigned long long u64;

constexpr int N_  = 256;
constexpr int CIN = 1024;
constexpr int H_  = 512;
constexpr int G4  = 2048;   // 4*H
constexpr int V_  = 32000;
constexpr int T_  = 8;

__device__ inline short f2bf(float f) {   // fp32 -> bf16 RNE
  union { float f; unsigned u; } v; v.f = f;
  unsigned r = v.u + 0x7fffu + ((v.u >> 16) & 1u);
  return (short)(r >> 16);
}
__device__ inline unsigned pk2(short a, short b) {
  return ((unsigned)(unsigned short)a) | (((unsigned)(unsigned short)b) << 16);
}

__device__ inline void async16(const void* g, void* l) {
  __builtin_amdgcn_global_load_lds((const GLOBAL_AS unsigned*)g,
                                   (LDS_AS unsigned*)l, 16, 0, 0);
}

__device__ inline float sigm(float x) { return 1.0f / (1.0f + __expf(-x)); }
__device__ inline float tanh_fast(float x) {
  x = fminf(15.0f, fmaxf(-15.0f, x));
  float e = __expf(2.0f * x);
  return (e - 1.0f) / (e + 1.0f);
}

// agent-coherent helpers (relaxed atomics -> plain ld/st with sc1; no fences)
__device__ inline void ag_store32(unsigned* p, unsigned v) {
  __hip_atomic_store(p, v, __ATOMIC_RELAXED, __HIP_MEMORY_SCOPE_AGENT);
}
__device__ inline u64 ag_load64(const u64* p) {
  return __hip_atomic_load(p, __ATOMIC_RELAXED, __HIP_MEMORY_SCOPE_AGENT);
}

// fence-free per-n-group barrier: all exchanged data is sc1-coherent, so
// ordering = vmcnt(0) drain (inside __syncthreads) + relaxed atomic counter.
__device__ inline void pbar(unsigned* cnt) {
  asm volatile("s_waitcnt vmcnt(0)" ::: "memory");   // defensive (barrier drains too)
  __syncthreads();
  if (threadIdx.x == 0) {
    unsigned v = __hip_atomic_fetch_add(cnt, 1u, __ATOMIC_RELAXED,
                                        __HIP_MEMORY_SCOPE_AGENT);
    unsigned tgt = (v & ~15u) + 16u;     // 16 arrivals per phase, monotone
    while (__hip_atomic_load(cnt, __ATOMIC_RELAXED, __HIP_MEMORY_SCOPE_AGENT) < tgt)
      __builtin_amdgcn_s_sleep(2);
  }
  __syncthreads();
}

// ---------------- fp32 -> bf16 for all 5 arrays + barrier zeroing -------------
__global__ __launch_bounds__(256) void cvt_all(
    const float* __restrict__ s0, short* __restrict__ d0, int c0,  // W_out
    const float* __restrict__ s1, short* __restrict__ d1, int c1,  // context
    const float* __restrict__ s2, short* __restrict__ d2, int c2,  // W_merge
    const float* __restrict__ s3, short* __restrict__ d3, int c3,  // W_ih
    const float* __restrict__ s4, short* __restrict__ d4, int c4,  // W_hh
    unsigned* __restrict__ bar) {
  int i = blockIdx.x * 256 + threadIdx.x;
  if (blockIdx.x == 0) bar[threadIdx.x] = 0u;   // re-zero every replay
  const float* s; short* d; int k;
  if (i < c0)                          { s = s0; d = d0; k = i; }
  else if (i < c0 + c1)                { s = s1; d = d1; k = i - c0; }
  else if (i < c0 + c1 + c2)           { s = s2; d = d2; k = i - c0 - c1; }
  else if (i < c0 + c1 + c2 + c3)      { s = s3; d = d3; k = i - c0 - c1 - c2; }
  else if (i < c0 + c1 + c2 + c3 + c4) { s = s4; d = d4; k = i - c0 - c1 - c2 - c3; }
  else return;
  float4 v = ((const float4*)s)[k];
  short4 o;
  o.x = f2bf(v.x); o.y = f2bf(v.y); o.z = f2bf(v.z); o.w = f2bf(v.w);
  ((short4*)d)[k] = o;
}

// ---------------- fused decoder core -----------------------------------------
// grid (16, 8): j0 = x*32, n0 = y*32. 256 thr = 4 waves, wave w = gate w.
// LDS: WhhL 128KB (ctx tile during phase 2, then persistent swizzled Whh)
//      + 32KB scratch (merge bufs / Bs / HL tile / G overlay).
__global__ __launch_bounds__(256, 1) void decoder_core(
    const short* __restrict__ Ctxin,   // [N][CIN] bf16
    const short* __restrict__ Wmrg,    // [H][CIN] bf16
    const float* __restrict__ bmrg,    // [H]
    const short* __restrict__ Wih,     // [G4][H] bf16
    const short* __restrict__ Whh,     // [G4][H] bf16
    const float* __restrict__ bih,
    const float* __restrict__ bhh,
    short* __restrict__ ctxg,          // [N][H] bf16 exchange buffer
    short* __restrict__ Hall,          // [T][N][H] bf16 out
    unsigned* __restrict__ bar)
{
  __shared__ alignas(16) short WhhL[128 * H_];   // 128 KB
  __shared__ alignas(16) char scratch[32768];    // 32 KB

  const int tid   = threadIdx.x;
  const int lane  = tid & 63;
  const int w     = tid >> 6;            // gate 0..3 (i,f,g,o)
  const int rlane = lane & 15;
  const int klane = (lane >> 4) * 8;     // shorts
  const int qrow  = (lane >> 4) * 4;     // C-layout row base
  const int j0    = blockIdx.x * 32;
  const int n0    = blockIdx.y * 32;
  unsigned* mybar = bar + blockIdx.y * 32;   // 128B-spaced counter per n-group
  const int swz   = (rlane & 7) << 4;        // read-side XOR (1024B-stride rows)
  const int hrow  = tid >> 3, hseg = tid & 7; // [32][512] tile-load mapping

  // ---- phase 1: merge GEMM  ctx[n0:+32][j0:+32] = context @ Wmrg^T + b ----
  // per-wave K-quarter, partials reduced through LDS. (Whh load NOT yet issued,
  // so the per-wave vmcnt(0) drains only our own 4 staging loads.)
  {
    short* Aw = (short*)scratch + w * 2048;   // [32][32] bf16 per wave
    short* Bw = Aw + 1024;
    f32x4 m00 = {0,0,0,0}, m01 = {0,0,0,0}, m10 = {0,0,0,0}, m11 = {0,0,0,0};
    const int kb = w * 256;
    for (int i = 0; i < 8; ++i) {
      int kc = kb + i * 32;
#pragma unroll
      for (int p = 0; p < 2; ++p) {
        int cA = p * 64 + lane;
        async16(Ctxin + (size_t)(n0 + (cA >> 2)) * CIN + kc + (cA & 3) * 8,
                Aw + p * 512);
        async16(Wmrg + (size_t)(j0 + (cA >> 2)) * CIN + kc + (cA & 3) * 8,
                Bw + p * 512);
      }
      asm volatile("s_waitcnt vmcnt(0)" ::: "memory");
      __builtin_amdgcn_sched_barrier(0);
      short8 ma0 = *(const short8*)&Aw[rlane * 32 + klane];
      short8 ma1 = *(const short8*)&Aw[(16 + rlane) * 32 + klane];
      short8 mb0 = *(const short8*)&Bw[rlane * 32 + klane];
      short8 mb1 = *(const short8*)&Bw[(16 + rlane) * 32 + klane];
      m00 = __builtin_amdgcn_mfma_f32_16x16x32_bf16(ma0, mb0, m00, 0, 0, 0);
      m01 = __builtin_amdgcn_mfma_f32_16x16x32_bf16(ma0, mb1, m01, 0, 0, 0);
      m10 = __builtin_amdgcn_mfma_f32_16x16x32_bf16(ma1, mb0, m10, 0, 0, 0);
      m11 = __builtin_amdgcn_mfma_f32_16x16x32_bf16(ma1, mb1, m11, 0, 0, 0);
      asm volatile("s_waitcnt lgkmcnt(0)" ::: "memory"); // WAR: reads landed
      __builtin_amdgcn_sched_barrier(0);
    }
    __syncthreads();
    float* G = (float*)scratch;           // [4][32][32] partials overlay
#pragma unroll
    for (int r = 0; r < 4; ++r) {
      G[(w * 32 + qrow + r) * 32 + rlane]           = m00[r];
      G[(w * 32 + qrow + r) * 32 + 16 + rlane]      = m01[r];
      G[(w * 32 + 16 + qrow + r) * 32 + rlane]      = m10[r];
      G[(w * 32 + 16 + qrow + r) * 32 + 16 + rlane] = m11[r];
    }
    __syncthreads();
    int nn = tid >> 3, jq = tid & 7;
    const float4* Gv = (const float4*)scratch;
    float4 p0 = Gv[(0 * 32 + nn) * 8 + jq];
    float4 p1 = Gv[(1 * 32 + nn) * 8 + jq];
    float4 p2 = Gv[(2 * 32 + nn) * 8 + jq];
    float4 p3 = Gv[(3 * 32 + nn) * 8 + jq];
    int jb = j0 + jq * 4;
    short e0 = f2bf(p0.x + p1.x + p2.x + p3.x + bmrg[jb + 0]);
    short e1 = f2bf(p0.y + p1.y + p2.y + p3.y + bmrg[jb + 1]);
    short e2 = f2bf(p0.z + p1.z + p2.z + p3.z + bmrg[jb + 2]);
    short e3 = f2bf(p0.w + p1.w + p2.w + p3.w + bmrg[jb + 3]);
    unsigned* cp = (unsigned*)&ctxg[(size_t)(n0 + nn) * H_ + jb];
    ag_store32(cp + 0, pk2(e0, e1));     // agent-coherent (sc1 write-through)
    ag_store32(cp + 1, pk2(e2, e3));
  }
  pbar(mybar);   // ctx rows n0:+32 complete across the 16 j-blocks

  // ---- load full ctx n-tile [32][512] into WhhL region (swizzled) ----
  {
    const u64* rp = (const u64*)(ctxg + (size_t)(n0 + hrow) * H_);
    u64 cv[16];
#pragma unroll
    for (int i = 0; i < 16; ++i)
      cv[i] = ag_load64(rp + i * 8 + hseg);     // MALL reads, bypass stale caches
    char* CL = (char*)WhhL;
#pragma unroll
    for (int i = 0; i < 16; ++i)
      *(u64*)(CL + ((hrow * 1024 + i * 64 + hseg * 8) ^ ((hrow & 7) << 4))) = cv[i];
  }
  __syncthreads();

  // ---- phase 2: x_proj in registers  xp = ctx @ Wih^T + b_ih + b_hh ----
  f32x4 x00, x01, x10, x11;
  {
    int ng0 = w * H_ + j0 + rlane, ng1 = ng0 + 16;
    float bc0 = bih[ng0] + bhh[ng0];
    float bc1 = bih[ng1] + bhh[ng1];
    x00 = (f32x4){bc0, bc0, bc0, bc0};  x01 = (f32x4){bc1, bc1, bc1, bc1};
    x10 = x00;                          x11 = x01;
    short* Bs = (short*)scratch;            // [128][32] (8 KB) streamed
    const char* CLb = (const char*)WhhL;    // ctx tile, swizzled
    for (int kc = 0; kc < H_; kc += 32) {
#pragma unroll
      for (int p = 0; p < 2; ++p) {
        int idx = p * 256 + tid;
        int br = idx >> 2, q = idx & 3;
        async16(Wih + (size_t)((br >> 5) * H_ + j0 + (br & 31)) * H_ + q * 8 + kc,
                &Bs[(idx & ~63) * 8]);
      }
      __syncthreads();
      int ko = (kc + klane) * 2;
      short8 xa0 = *(const short8*)(CLb + ((rlane * 1024 + ko) ^ swz));
      short8 xa1 = *(const short8*)(CLb + (((16 + rlane) * 1024 + ko) ^ swz));
      short8 xb0 = *(const short8*)&Bs[(w * 32 + rlane) * 32 + klane];
      short8 xb1 = *(const short8*)&Bs[(w * 32 + 16 + rlane) * 32 + klane];
      x00 = __builtin_amdgcn_mfma_f32_16x16x32_bf16(xa0, xb0, x00, 0, 0, 0);
      x01 = __builtin_amdgcn_mfma_f32_16x16x32_bf16(xa0, xb1, x01, 0, 0, 0);
      x10 = __builtin_amdgcn_mfma_f32_16x16x32_bf16(xa1, xb0, x10, 0, 0, 0);
      x11 = __builtin_amdgcn_mfma_f32_16x16x32_bf16(xa1, xb1, x11, 0, 0, 0);
      __syncthreads();
    }
  }

  // ---- issue persistent Whh slice load (overwrites ctx tile; first read t=1,
  //      every intervening __syncthreads drains vmcnt, so it will have landed)
  // Linear LDS dest + pre-swizzled global k so read addr ^((row&7)<<4) works.
#pragma unroll
  for (int i = 0; i < 32; ++i) {
    int c = i * 256 + tid;                  // 16B chunk id, 64 chunks/row
    int r = c >> 6, cq = c & 63;
    int ks = ((cq << 4) ^ ((r & 7) << 4)) >> 1;   // source short offset in row
    async16(Whh + (size_t)((r >> 5) * H_ + j0 + (r & 31)) * H_ + ks,
            &WhhL[(size_t)(i * 256 + (tid & ~63)) * 8]);
  }

  // ---- phase 3: 8 LSTM steps; c in registers; Whh from persistent LDS ----
  float creg[4] = {0.f, 0.f, 0.f, 0.f};
  const int ne = tid >> 3, jq = tid & 7;
  const int r_b0 = w * 32 + rlane, r_b1 = r_b0 + 16;
  const char* WLb = (const char*)WhhL;
  char* HLb = (char*)scratch;              // [32][512] swizzled Hprev tile

  for (int t = 0; t < T_; ++t) {
    f32x4 a00 = x00, a01 = x01, a10 = x10, a11 = x11;
    if (t > 0) {
      const short* Hp = Hall + (size_t)(t - 1) * N_ * H_;
      const u64* rp = (const u64*)(Hp + (size_t)(n0 + hrow) * H_);
      u64 hv[16];
#pragma unroll
      for (int i = 0; i < 16; ++i)
        hv[i] = ag_load64(rp + i * 8 + hseg);   // coherent MALL reads
#pragma unroll
      for (int i = 0; i < 16; ++i)
        *(u64*)(HLb + ((hrow * 1024 + i * 64 + hseg * 8) ^ ((hrow & 7) << 4))) = hv[i];
      __syncthreads();                     // HL valid (+ Whh landed for t=1)
#pragma unroll
      for (int kc = 0; kc < H_; kc += 32) {   // barrier-free LDS->MFMA K-loop
        int ko = (kc + klane) * 2;
        short8 a0 = *(const short8*)(HLb + ((rlane * 1024 + ko) ^ swz));
        short8 a1 = *(const short8*)(HLb + (((16 + rlane) * 1024 + ko) ^ swz));
        short8 b0 = *(const short8*)(WLb + ((r_b0 * 1024 + ko) ^ swz));
        short8 b1 = *(const short8*)(WLb + ((r_b1 * 1024 + ko) ^ swz));
        a00 = __builtin_amdgcn_mfma_f32_16x16x32_bf16(a0, b0, a00, 0, 0, 0);
        a01 = __builtin_amdgcn_mfma_f32_16x16x32_bf16(a0, b1, a01, 0, 0, 0);
        a10 = __builtin_amdgcn_mfma_f32_16x16x32_bf16(a1, b0, a10, 0, 0, 0);
        a11 = __builtin_amdgcn_mfma_f32_16x16x32_bf16(a1, b1, a11, 0, 0, 0);
      }
      __syncthreads();                     // HL reads done before G overlay
    }
    // gate exchange via LDS: G[gate][n][j]
    float* G = (float*)scratch;
#pragma unroll
    for (int r = 0; r < 4; ++r) {
      G[(w * 32 + qrow + r) * 32 + rlane]           = a00[r];
      G[(w * 32 + qrow + r) * 32 + 16 + rlane]      = a01[r];
      G[(w * 32 + 16 + qrow + r) * 32 + rlane]      = a10[r];
      G[(w * 32 + 16 + qrow + r) * 32 + 16 + rlane] = a11[r];
    }
    __syncthreads();
    float4 gi = ((const float4*)G)[(0 * 32 + ne) * 8 + jq];
    float4 gf = ((const float4*)G)[(1 * 32 + ne) * 8 + jq];
    float4 gg = ((const float4*)G)[(2 * 32 + ne) * 8 + jq];
    float4 go = ((const float4*)G)[(3 * 32 + ne) * 8 + jq];
    float pi[4] = {gi.x, gi.y, gi.z, gi.w};
    float pf[4] = {gf.x, gf.y, gf.z, gf.w};
    float pg[4] = {gg.x, gg.y, gg.z, gg.w};
    float po[4] = {go.x, go.y, go.z, go.w};
    short hv4[4];
#pragma unroll
    for (int e = 0; e < 4; ++e) {
      float ii = sigm(pi[e]), ff = sigm(pf[e]);
      float g2 = tanh_fast(pg[e]), oo = sigm(po[e]);
      float cv = ff * creg[e] + ii * g2;   // t=0: creg=0 == h0,c0=0
      creg[e] = cv;
      hv4[e] = f2bf(oo * tanh_fast(cv));
    }
    unsigned* hp = (unsigned*)&Hall[(size_t)t * N_ * H_
                                    + (size_t)(n0 + ne) * H_ + j0 + jq * 4];
    ag_store32(hp + 0, pk2(hv4[0], hv4[1]));   // agent-coherent h publish
    ag_store32(hp + 1, pk2(hv4[2], hv4[3]));
    if (t < T_ - 1) pbar(mybar);               // Hall[t] visible to n-group
  }
}

// ------------- bf16 MFMA GEMM-BT: C[M,N] = A[M,K] @ B[N,K]^T -----------------
// MODE 2: C fp32, row m = t*256+n remapped to out[n][t][v], + bias1.
template<int BM, int BN, int MODE>
__global__ __launch_bounds__(256) void gemm_bf16_bt(
    const short* __restrict__ A, const short* __restrict__ B,
    const float* __restrict__ bias1, const float* __restrict__ bias2,
    void* __restrict__ Cv, int M, int N, int K)
{
  constexpr int RT = BM / 32;
  constexpr int CT = BN / 32;
  __shared__ short As[BM * 32];
  __shared__ short Bs[BN * 32];

  const int tid = threadIdx.x;
  const int lane = tid & 63;
  const int w = tid >> 6;
  const int wr = w >> 1, wc = w & 1;
  const int m0 = blockIdx.y * BM;
  const int n0 = blockIdx.x * BN;
  const int rlane = lane & 15;
  const int klane = (lane >> 4) * 8;

  f32x4 acc[RT][CT] = {};

  for (int kc = 0; kc < K; kc += 32) {
#pragma unroll
    for (int it = 0; it < (BM * 4) / 256; ++it) {
      int idx = it * 256 + tid;
      const short* g = A + (size_t)(m0 + (idx >> 2)) * K + kc + (idx & 3) * 8;
      async16(g, &As[(size_t)(it * 256 + (tid & ~63)) * 8]);
    }
#pragma unroll
    for (int it = 0; it < (BN * 4) / 256; ++it) {
      int idx = it * 256 + tid;
      const short* g = B + (size_t)(n0 + (idx >> 2)) * K + kc + (idx & 3) * 8;
      async16(g, &Bs[(size_t)(it * 256 + (tid & ~63)) * 8]);
    }
    __syncthreads();

    short8 af[RT], bfr[CT];
#pragma unroll
    for (int rt = 0; rt < RT; ++rt)
      af[rt] = *(const short8*)&As[(wr * (RT * 16) + rt * 16 + rlane) * 32 + klane];
#pragma unroll
    for (int ct = 0; ct < CT; ++ct)
      bfr[ct] = *(const short8*)&Bs[(wc * (CT * 16) + ct * 16 + rlane) * 32 + klane];
#pragma unroll
    for (int rt = 0; rt < RT; ++rt)
#pragma unroll
      for (int ct = 0; ct < CT; ++ct)
        acc[rt][ct] = __builtin_amdgcn_mfma_f32_16x16x32_bf16(af[rt], bfr[ct],
                                                              acc[rt][ct], 0, 0, 0);
    __syncthreads();
  }

  // C/D layout: col = lane&15, row = (lane>>4)*4 + reg
#pragma unroll
  for (int ct = 0; ct < CT; ++ct) {
    int ng = n0 + wc * (CT * 16) + ct * 16 + rlane;
    float bv = (bias1 ? bias1[ng] : 0.0f) + (bias2 ? bias2[ng] : 0.0f);
#pragma unroll
    for (int rt = 0; rt < RT; ++rt)
#pragma unroll
      for (int r = 0; r < 4; ++r) {
        int mg = m0 + wr * (RT * 16) + rt * 16 + (lane >> 4) * 4 + r;
        float v = acc[rt][ct][r] + bv;
        if (MODE == 2) {
          int t = mg >> 8, nb = mg & 255;
          ((float*)Cv)[(size_t)nb * (T_ * V_) + (size_t)t * V_ + ng] = v;
        } else if (MODE == 1) {
          ((short*)Cv)[(size_t)mg * N + ng] = f2bf(v);
        } else {
          ((float*)Cv)[(size_t)mg * N + ng] = v;
        }
      }
  }
}

extern "C" void kernel_launch(void* const* d_in, const int* in_sizes, int n_in,
                              void* d_out, int out_size, void* d_ws, size_t ws_size,
                              hipStream_t stream)
{
  (void)in_sizes; (void)n_in; (void)out_size; (void)ws_size;
  const float* context = (const float*)d_in[0];
  const float* W_merge = (const float*)d_in[1];
  const float* b_merge = (const float*)d_in[2];
  const float* W_ih    = (const float*)d_in[3];
  const float* W_hh    = (const float*)d_in[4];
  const float* b_ih    = (const float*)d_in[5];
  const float* b_hh    = (const float*)d_in[6];
  const float* W_out   = (const float*)d_in[7];
  const float* b_out   = (const float*)d_in[8];
  float* out = (float*)d_out;

  // workspace layout (~40 MB)
  char* p = (char*)d_ws;
  short* Wout_b  = (short*)p;  p += (size_t)V_ * H_ * 2;       // 32.77 MB
  short* Whh_b   = (short*)p;  p += (size_t)G4 * H_ * 2;       // 2 MB
  short* Wih_b   = (short*)p;  p += (size_t)G4 * H_ * 2;       // 2 MB
  short* Wmrg_b  = (short*)p;  p += (size_t)H_ * CIN * 2;      // 1 MB
  short* Ctxin_b = (short*)p;  p += (size_t)N_ * CIN * 2;      // 0.5 MB
  short* Ctx_b   = (short*)p;  p += (size_t)N_ * H_ * 2;       // 0.25 MB
  short* Hall    = (short*)p;  p += (size_t)T_ * N_ * H_ * 2;  // 2 MB [t][n][k]
  unsigned* bar  = (unsigned*)p; p += 256 * 4;                 // 1 KB barriers

  // 1) all conversions + barrier zeroing (one launch)
  {
    int c0 = V_ * H_ / 4, c1 = N_ * CIN / 4, c2 = H_ * CIN / 4;
    int c3 = G4 * H_ / 4, c4 = G4 * H_ / 4;
    int tot = c0 + c1 + c2 + c3 + c4;
    cvt_all<<<(tot + 255) / 256, 256, 0, stream>>>(
        W_out, Wout_b, c0, context, Ctxin_b, c1, W_merge, Wmrg_b, c2,
        W_ih, Wih_b, c3, W_hh, Whh_b, c4, bar);
  }

  // 2) fused merge + x_proj + 8 LSTM steps (fence-free device barriers)
  decoder_core<<<dim3(H_ / 32, N_ / 32), 256, 0, stream>>>(
      Ctxin_b, Wmrg_b, b_merge, Wih_b, Whh_b, b_ih, b_hh, Ctx_b, Hall, bar);

  // 3) logits: [2048 x 32000] = Hall @ W_out^T + b_out -> out[N,T,V]
  gemm_bf16_bt<128, 128, 2><<<dim3(V_ / 128, (T_ * N_) / 128), 256, 0, stream>>>(
      Hall, Wout_b, b_out, nullptr, out, T_ * N_, V_, H_);
}

// Round 3
// 459.027 us; speedup vs baseline: 1.3434x; 1.0849x over previous
//
#include <hip/hip_runtime.h>

// VarDecoder: N=256, CAT_IN=1024, H=512, V=32000, T=8
// Round 5: logits GEMM rebuilt — BK=64 double-buffered 2-phase with counted
//   vmcnt (raw s_barrier, never a full drain in the K-loop), row-XOR LDS
//   swizzle (rule-21: pre-swizzled global source + XOR on ds_read), and
//   XCD-chunked block swizzle with m-fastest order so each Wout 128-row panel
//   is consumed by 16 same-XCD blocks (B HBM traffic 512MB -> 32MB).
// cvt_all + decoder_core unchanged from round 4 (passed, 498 us).
// 3 launches: cvt_all, decoder_core, gemm_logits.

#define GLOBAL_AS __attribute__((address_space(1)))
#define LDS_AS __attribute__((address_space(3)))

typedef __attribute__((ext_vector_type(8))) short short8;   // 8 x bf16
typedef __attribute__((ext_vector_type(4))) float f32x4;    // MFMA accumulator
typedef unsigned long long u64;

constexpr int N_  = 256;
constexpr int CIN = 1024;
constexpr int H_  = 512;
constexpr int G4  = 2048;   // 4*H
constexpr int V_  = 32000;
constexpr int T_  = 8;

__device__ inline short f2bf(float f) {   // fp32 -> bf16 RNE
  union { float f; unsigned u; } v; v.f = f;
  unsigned r = v.u + 0x7fffu + ((v.u >> 16) & 1u);
  return (short)(r >> 16);
}
__device__ inline unsigned pk2(short a, short b) {
  return ((unsigned)(unsigned short)a) | (((unsigned)(unsigned short)b) << 16);
}

__device__ inline void async16(const void* g, void* l) {
  __builtin_amdgcn_global_load_lds((const GLOBAL_AS unsigned*)g,
                                   (LDS_AS unsigned*)l, 16, 0, 0);
}

__device__ inline float sigm(float x) { return 1.0f / (1.0f + __expf(-x)); }
__device__ inline float tanh_fast(float x) {
  x = fminf(15.0f, fmaxf(-15.0f, x));
  float e = __expf(2.0f * x);
  return (e - 1.0f) / (e + 1.0f);
}

// agent-coherent helpers (relaxed atomics -> plain ld/st with sc1; no fences)
__device__ inline void ag_store32(unsigned* p, unsigned v) {
  __hip_atomic_store(p, v, __ATOMIC_RELAXED, __HIP_MEMORY_SCOPE_AGENT);
}
__device__ inline u64 ag_load64(const u64* p) {
  return __hip_atomic_load(p, __ATOMIC_RELAXED, __HIP_MEMORY_SCOPE_AGENT);
}

// fence-free per-n-group barrier (16 arrivals), exchanged data is sc1-coherent
__device__ inline void pbar(unsigned* cnt) {
  asm volatile("s_waitcnt vmcnt(0)" ::: "memory");
  __syncthreads();
  if (threadIdx.x == 0) {
    unsigned v = __hip_atomic_fetch_add(cnt, 1u, __ATOMIC_RELAXED,
                                        __HIP_MEMORY_SCOPE_AGENT);
    unsigned tgt = (v & ~15u) + 16u;
    while (__hip_atomic_load(cnt, __ATOMIC_RELAXED, __HIP_MEMORY_SCOPE_AGENT) < tgt)
      __builtin_amdgcn_s_sleep(2);
  }
  __syncthreads();
}

// ---------------- fp32 -> bf16 for all 5 arrays + barrier zeroing -------------
__global__ __launch_bounds__(256) void cvt_all(
    const float* __restrict__ s0, short* __restrict__ d0, int c0,  // W_out
    const float* __restrict__ s1, short* __restrict__ d1, int c1,  // context
    const float* __restrict__ s2, short* __restrict__ d2, int c2,  // W_merge
    const float* __restrict__ s3, short* __restrict__ d3, int c3,  // W_ih
    const float* __restrict__ s4, short* __restrict__ d4, int c4,  // W_hh
    unsigned* __restrict__ bar) {
  int i = blockIdx.x * 256 + threadIdx.x;
  if (blockIdx.x == 0) bar[threadIdx.x] = 0u;   // re-zero every replay
  const float* s; short* d; int k;
  if (i < c0)                          { s = s0; d = d0; k = i; }
  else if (i < c0 + c1)                { s = s1; d = d1; k = i - c0; }
  else if (i < c0 + c1 + c2)           { s = s2; d = d2; k = i - c0 - c1; }
  else if (i < c0 + c1 + c2 + c3)      { s = s3; d = d3; k = i - c0 - c1 - c2; }
  else if (i < c0 + c1 + c2 + c3 + c4) { s = s4; d = d4; k = i - c0 - c1 - c2 - c3; }
  else return;
  float4 v = ((const float4*)s)[k];
  short4 o;
  o.x = f2bf(v.x); o.y = f2bf(v.y); o.z = f2bf(v.z); o.w = f2bf(v.w);
  ((short4*)d)[k] = o;
}

// ---------------- fused decoder core (unchanged from round 4) -----------------
__global__ __launch_bounds__(256, 1) void decoder_core(
    const short* __restrict__ Ctxin,   // [N][CIN] bf16
    const short* __restrict__ Wmrg,    // [H][CIN] bf16
    const float* __restrict__ bmrg,    // [H]
    const short* __restrict__ Wih,     // [G4][H] bf16
    const short* __restrict__ Whh,     // [G4][H] bf16
    const float* __restrict__ bih,
    const float* __restrict__ bhh,
    short* __restrict__ ctxg,          // [N][H] bf16 exchange buffer
    short* __restrict__ Hall,          // [T][N][H] bf16 out
    unsigned* __restrict__ bar)
{
  __shared__ alignas(16) short WhhL[128 * H_];   // 128 KB
  __shared__ alignas(16) char scratch[32768];    // 32 KB

  const int tid   = threadIdx.x;
  const int lane  = tid & 63;
  const int w     = tid >> 6;            // gate 0..3 (i,f,g,o)
  const int rlane = lane & 15;
  const int klane = (lane >> 4) * 8;     // shorts
  const int qrow  = (lane >> 4) * 4;     // C-layout row base
  const int j0    = blockIdx.x * 32;
  const int n0    = blockIdx.y * 32;
  unsigned* mybar = bar + blockIdx.y * 32;
  const int swz   = (rlane & 7) << 4;
  const int hrow  = tid >> 3, hseg = tid & 7;

  // ---- phase 1: merge GEMM ----
  {
    short* Aw = (short*)scratch + w * 2048;
    short* Bw = Aw + 1024;
    f32x4 m00 = {0,0,0,0}, m01 = {0,0,0,0}, m10 = {0,0,0,0}, m11 = {0,0,0,0};
    const int kb = w * 256;
    for (int i = 0; i < 8; ++i) {
      int kc = kb + i * 32;
#pragma unroll
      for (int p = 0; p < 2; ++p) {
        int cA = p * 64 + lane;
        async16(Ctxin + (size_t)(n0 + (cA >> 2)) * CIN + kc + (cA & 3) * 8,
                Aw + p * 512);
        async16(Wmrg + (size_t)(j0 + (cA >> 2)) * CIN + kc + (cA & 3) * 8,
                Bw + p * 512);
      }
      asm volatile("s_waitcnt vmcnt(0)" ::: "memory");
      __builtin_amdgcn_sched_barrier(0);
      short8 ma0 = *(const short8*)&Aw[rlane * 32 + klane];
      short8 ma1 = *(const short8*)&Aw[(16 + rlane) * 32 + klane];
      short8 mb0 = *(const short8*)&Bw[rlane * 32 + klane];
      short8 mb1 = *(const short8*)&Bw[(16 + rlane) * 32 + klane];
      m00 = __builtin_amdgcn_mfma_f32_16x16x32_bf16(ma0, mb0, m00, 0, 0, 0);
      m01 = __builtin_amdgcn_mfma_f32_16x16x32_bf16(ma0, mb1, m01, 0, 0, 0);
      m10 = __builtin_amdgcn_mfma_f32_16x16x32_bf16(ma1, mb0, m10, 0, 0, 0);
      m11 = __builtin_amdgcn_mfma_f32_16x16x32_bf16(ma1, mb1, m11, 0, 0, 0);
      asm volatile("s_waitcnt lgkmcnt(0)" ::: "memory");
      __builtin_amdgcn_sched_barrier(0);
    }
    __syncthreads();
    float* G = (float*)scratch;
#pragma unroll
    for (int r = 0; r < 4; ++r) {
      G[(w * 32 + qrow + r) * 32 + rlane]           = m00[r];
      G[(w * 32 + qrow + r) * 32 + 16 + rlane]      = m01[r];
      G[(w * 32 + 16 + qrow + r) * 32 + rlane]      = m10[r];
      G[(w * 32 + 16 + qrow + r) * 32 + 16 + rlane] = m11[r];
    }
    __syncthreads();
    int nn = tid >> 3, jq = tid & 7;
    const float4* Gv = (const float4*)scratch;
    float4 p0 = Gv[(0 * 32 + nn) * 8 + jq];
    float4 p1 = Gv[(1 * 32 + nn) * 8 + jq];
    float4 p2 = Gv[(2 * 32 + nn) * 8 + jq];
    float4 p3 = Gv[(3 * 32 + nn) * 8 + jq];
    int jb = j0 + jq * 4;
    short e0 = f2bf(p0.x + p1.x + p2.x + p3.x + bmrg[jb + 0]);
    short e1 = f2bf(p0.y + p1.y + p2.y + p3.y + bmrg[jb + 1]);
    short e2 = f2bf(p0.z + p1.z + p2.z + p3.z + bmrg[jb + 2]);
    short e3 = f2bf(p0.w + p1.w + p2.w + p3.w + bmrg[jb + 3]);
    unsigned* cp = (unsigned*)&ctxg[(size_t)(n0 + nn) * H_ + jb];
    ag_store32(cp + 0, pk2(e0, e1));
    ag_store32(cp + 1, pk2(e2, e3));
  }
  pbar(mybar);

  // ---- load full ctx n-tile [32][512] into WhhL region (swizzled) ----
  {
    const u64* rp = (const u64*)(ctxg + (size_t)(n0 + hrow) * H_);
    u64 cv[16];
#pragma unroll
    for (int i = 0; i < 16; ++i)
      cv[i] = ag_load64(rp + i * 8 + hseg);
    char* CL = (char*)WhhL;
#pragma unroll
    for (int i = 0; i < 16; ++i)
      *(u64*)(CL + ((hrow * 1024 + i * 64 + hseg * 8) ^ ((hrow & 7) << 4))) = cv[i];
  }
  __syncthreads();

  // ---- phase 2: x_proj in registers ----
  f32x4 x00, x01, x10, x11;
  {
    int ng0 = w * H_ + j0 + rlane, ng1 = ng0 + 16;
    float bc0 = bih[ng0] + bhh[ng0];
    float bc1 = bih[ng1] + bhh[ng1];
    x00 = (f32x4){bc0, bc0, bc0, bc0};  x01 = (f32x4){bc1, bc1, bc1, bc1};
    x10 = x00;                          x11 = x01;
    short* Bs = (short*)scratch;
    const char* CLb = (const char*)WhhL;
    for (int kc = 0; kc < H_; kc += 32) {
#pragma unroll
      for (int p = 0; p < 2; ++p) {
        int idx = p * 256 + tid;
        int br = idx >> 2, q = idx & 3;
        async16(Wih + (size_t)((br >> 5) * H_ + j0 + (br & 31)) * H_ + q * 8 + kc,
                &Bs[(idx & ~63) * 8]);
      }
      __syncthreads();
      int ko = (kc + klane) * 2;
      short8 xa0 = *(const short8*)(CLb + ((rlane * 1024 + ko) ^ swz));
      short8 xa1 = *(const short8*)(CLb + (((16 + rlane) * 1024 + ko) ^ swz));
      short8 xb0 = *(const short8*)&Bs[(w * 32 + rlane) * 32 + klane];
      short8 xb1 = *(const short8*)&Bs[(w * 32 + 16 + rlane) * 32 + klane];
      x00 = __builtin_amdgcn_mfma_f32_16x16x32_bf16(xa0, xb0, x00, 0, 0, 0);
      x01 = __builtin_amdgcn_mfma_f32_16x16x32_bf16(xa0, xb1, x01, 0, 0, 0);
      x10 = __builtin_amdgcn_mfma_f32_16x16x32_bf16(xa1, xb0, x10, 0, 0, 0);
      x11 = __builtin_amdgcn_mfma_f32_16x16x32_bf16(xa1, xb1, x11, 0, 0, 0);
      __syncthreads();
    }
  }

  // ---- persistent Whh slice load (first read t=1) ----
#pragma unroll
  for (int i = 0; i < 32; ++i) {
    int c = i * 256 + tid;
    int r = c >> 6, cq = c & 63;
    int ks = ((cq << 4) ^ ((r & 7) << 4)) >> 1;
    async16(Whh + (size_t)((r >> 5) * H_ + j0 + (r & 31)) * H_ + ks,
            &WhhL[(size_t)(i * 256 + (tid & ~63)) * 8]);
  }

  // ---- phase 3: 8 LSTM steps ----
  float creg[4] = {0.f, 0.f, 0.f, 0.f};
  const int ne = tid >> 3, jq = tid & 7;
  const int r_b0 = w * 32 + rlane, r_b1 = r_b0 + 16;
  const char* WLb = (const char*)WhhL;
  char* HLb = (char*)scratch;

  for (int t = 0; t < T_; ++t) {
    f32x4 a00 = x00, a01 = x01, a10 = x10, a11 = x11;
    if (t > 0) {
      const short* Hp = Hall + (size_t)(t - 1) * N_ * H_;
      const u64* rp = (const u64*)(Hp + (size_t)(n0 + hrow) * H_);
      u64 hv[16];
#pragma unroll
      for (int i = 0; i < 16; ++i)
        hv[i] = ag_load64(rp + i * 8 + hseg);
#pragma unroll
      for (int i = 0; i < 16; ++i)
        *(u64*)(HLb + ((hrow * 1024 + i * 64 + hseg * 8) ^ ((hrow & 7) << 4))) = hv[i];
      __syncthreads();
#pragma unroll
      for (int kc = 0; kc < H_; kc += 32) {
        int ko = (kc + klane) * 2;
        short8 a0 = *(const short8*)(HLb + ((rlane * 1024 + ko) ^ swz));
        short8 a1 = *(const short8*)(HLb + (((16 + rlane) * 1024 + ko) ^ swz));
        short8 b0 = *(const short8*)(WLb + ((r_b0 * 1024 + ko) ^ swz));
        short8 b1 = *(const short8*)(WLb + ((r_b1 * 1024 + ko) ^ swz));
        a00 = __builtin_amdgcn_mfma_f32_16x16x32_bf16(a0, b0, a00, 0, 0, 0);
        a01 = __builtin_amdgcn_mfma_f32_16x16x32_bf16(a0, b1, a01, 0, 0, 0);
        a10 = __builtin_amdgcn_mfma_f32_16x16x32_bf16(a1, b0, a10, 0, 0, 0);
        a11 = __builtin_amdgcn_mfma_f32_16x16x32_bf16(a1, b1, a11, 0, 0, 0);
      }
      __syncthreads();
    }
    float* G = (float*)scratch;
#pragma unroll
    for (int r = 0; r < 4; ++r) {
      G[(w * 32 + qrow + r) * 32 + rlane]           = a00[r];
      G[(w * 32 + qrow + r) * 32 + 16 + rlane]      = a01[r];
      G[(w * 32 + 16 + qrow + r) * 32 + rlane]      = a10[r];
      G[(w * 32 + 16 + qrow + r) * 32 + 16 + rlane] = a11[r];
    }
    __syncthreads();
    float4 gi = ((const float4*)G)[(0 * 32 + ne) * 8 + jq];
    float4 gf = ((const float4*)G)[(1 * 32 + ne) * 8 + jq];
    float4 gg = ((const float4*)G)[(2 * 32 + ne) * 8 + jq];
    float4 go = ((const float4*)G)[(3 * 32 + ne) * 8 + jq];
    float pi[4] = {gi.x, gi.y, gi.z, gi.w};
    float pf[4] = {gf.x, gf.y, gf.z, gf.w};
    float pg[4] = {gg.x, gg.y, gg.z, gg.w};
    float po[4] = {go.x, go.y, go.z, go.w};
    short hv4[4];
#pragma unroll
    for (int e = 0; e < 4; ++e) {
      float ii = sigm(pi[e]), ff = sigm(pf[e]);
      float g2 = tanh_fast(pg[e]), oo = sigm(po[e]);
      float cv = ff * creg[e] + ii * g2;
      creg[e] = cv;
      hv4[e] = f2bf(oo * tanh_fast(cv));
    }
    unsigned* hp = (unsigned*)&Hall[(size_t)t * N_ * H_
                                    + (size_t)(n0 + ne) * H_ + j0 + jq * 4];
    ag_store32(hp + 0, pk2(hv4[0], hv4[1]));
    ag_store32(hp + 1, pk2(hv4[2], hv4[3]));
    if (t < T_ - 1) pbar(mybar);
  }
}

// ---------------- logits GEMM: out[n][t][v] = Hall @ Wout^T + b --------------
// 128x128 tile, BK=64 double-buffered, counted vmcnt(8) + raw s_barrier (no
// full drain in loop). Row-XOR LDS swizzle via pre-swizzled global source.
// XCD-chunked block order, m-fastest: 16 same-XCD blocks share each B panel.
__global__ __launch_bounds__(256) void gemm_logits(
    const short* __restrict__ A,   // Hall  [2048][512] bf16
    const short* __restrict__ B,   // Wout  [32000][512] bf16
    const float* __restrict__ bias,
    float* __restrict__ out)       // [256][8][32000] fp32
{
  constexpr int BK = 64;
  constexpr int NT = H_ / BK;      // 8 K-tiles
  __shared__ alignas(16) short As[2][128 * BK];   // 16 KB each
  __shared__ alignas(16) short Bs[2][128 * BK];

  const int tid   = threadIdx.x;
  const int lane  = tid & 63;
  const int w     = tid >> 6;
  const int wr    = w >> 1, wc = w & 1;
  const int rlane = lane & 15;
  const int klane = (lane >> 4) * 8;     // shorts within 32-k subtile

  // XCD-chunked swizzle: 4000 blocks, 8 XCDs, 500/chunk; m fastest (16 m-tiles
  // per n-tile are consecutive lids -> same chunk -> same XCD -> B L2-resident)
  int bid = (int)blockIdx.x;
  int lid = (bid & 7) * 500 + (bid >> 3);
  const int m0 = (lid & 15) * 128;       // 16 m-tiles
  const int n0 = (lid >> 4) * 128;       // 250 n-tiles

  f32x4 acc[4][4] = {};

  // stage K-tile kt into buffer b: linear LDS dest, source seg pre-swizzled
  // so read addr = (row*128 + c) ^ ((row&7)<<4) yields logical (row, c).
  auto stage = [&](int b, int kt) {
    const int kc = kt * BK;
#pragma unroll
    for (int it = 0; it < 4; ++it) {          // A: 1024 x 16B chunks
      int idx = it * 256 + tid;
      int r = idx >> 3, sg = idx & 7;
      async16(A + (size_t)(m0 + r) * H_ + kc + ((sg ^ (r & 7)) << 3),
              &As[b][(idx & ~63) * 8]);
    }
#pragma unroll
    for (int it = 0; it < 4; ++it) {          // B: 1024 x 16B chunks
      int idx = it * 256 + tid;
      int r = idx >> 3, sg = idx & 7;
      async16(B + (size_t)(n0 + r) * H_ + kc + ((sg ^ (r & 7)) << 3),
              &Bs[b][(idx & ~63) * 8]);
    }
  };

  stage(0, 0);
  for (int kt = 0; kt < NT; ++kt) {
    const int cur = kt & 1;
    if (kt + 1 < NT) {
      stage(cur ^ 1, kt + 1);                 // prefetch next tile
      asm volatile("s_waitcnt vmcnt(8)" ::: "memory");   // cur's 8 landed
    } else {
      asm volatile("s_waitcnt vmcnt(0)" ::: "memory");
    }
    __builtin_amdgcn_sched_barrier(0);
    __builtin_amdgcn_s_barrier();             // cur ready for all waves
    const char* Ab = (const char*)As[cur];
    const char* Bb = (const char*)Bs[cur];
#pragma unroll
    for (int ks = 0; ks < 2; ++ks) {
      short8 af[4], bf[4];
#pragma unroll
      for (int rt = 0; rt < 4; ++rt) {
        int row = wr * 64 + rt * 16 + rlane;
        af[rt] = *(const short8*)(Ab +
            ((row * 128 + ks * 64 + klane * 2) ^ ((row & 7) << 4)));
      }
#pragma unroll
      for (int ct = 0; ct < 4; ++ct) {
        int row = wc * 64 + ct * 16 + rlane;
        bf[ct] = *(const short8*)(Bb +
            ((row * 128 + ks * 64 + klane * 2) ^ ((row & 7) << 4)));
      }
      asm volatile("s_waitcnt lgkmcnt(0)" ::: "memory");
      __builtin_amdgcn_sched_barrier(0);
      __builtin_amdgcn_s_setprio(1);
#pragma unroll
      for (int rt = 0; rt < 4; ++rt)
#pragma unroll
        for (int ct = 0; ct < 4; ++ct)
          acc[rt][ct] = __builtin_amdgcn_mfma_f32_16x16x32_bf16(
              af[rt], bf[ct], acc[rt][ct], 0, 0, 0);
      __builtin_amdgcn_s_setprio(0);
    }
    __builtin_amdgcn_s_barrier();             // all reads of cur done before overwrite
  }

  // epilogue: C/D layout col=lane&15, row=(lane>>4)*4+reg; scatter to [n][t][v]
#pragma unroll
  for (int ct = 0; ct < 4; ++ct) {
    int ng = n0 + wc * 64 + ct * 16 + rlane;
    float bv = bias[ng];
#pragma unroll
    for (int rt = 0; rt < 4; ++rt)
#pragma unroll
      for (int r = 0; r < 4; ++r) {
        int mg = m0 + wr * 64 + rt * 16 + (lane >> 4) * 4 + r;
        int t = mg >> 8, nb = mg & 255;
        out[(size_t)nb * (T_ * V_) + (size_t)t * V_ + ng] = acc[rt][ct][r] + bv;
      }
  }
}

extern "C" void kernel_launch(void* const* d_in, const int* in_sizes, int n_in,
                              void* d_out, int out_size, void* d_ws, size_t ws_size,
                              hipStream_t stream)
{
  (void)in_sizes; (void)n_in; (void)out_size; (void)ws_size;
  const float* context = (const float*)d_in[0];
  const float* W_merge = (const float*)d_in[1];
  const float* b_merge = (const float*)d_in[2];
  const float* W_ih    = (const float*)d_in[3];
  const float* W_hh    = (const float*)d_in[4];
  const float* b_ih    = (const float*)d_in[5];
  const float* b_hh    = (const float*)d_in[6];
  const float* W_out   = (const float*)d_in[7];
  const float* b_out   = (const float*)d_in[8];
  float* out = (float*)d_out;

  // workspace layout (~40 MB)
  char* p = (char*)d_ws;
  short* Wout_b  = (short*)p;  p += (size_t)V_ * H_ * 2;       // 32.77 MB
  short* Whh_b   = (short*)p;  p += (size_t)G4 * H_ * 2;       // 2 MB
  short* Wih_b   = (short*)p;  p += (size_t)G4 * H_ * 2;       // 2 MB
  short* Wmrg_b  = (short*)p;  p += (size_t)H_ * CIN * 2;      // 1 MB
  short* Ctxin_b = (short*)p;  p += (size_t)N_ * CIN * 2;      // 0.5 MB
  short* Ctx_b   = (short*)p;  p += (size_t)N_ * H_ * 2;       // 0.25 MB
  short* Hall    = (short*)p;  p += (size_t)T_ * N_ * H_ * 2;  // 2 MB [t][n][k]
  unsigned* bar  = (unsigned*)p; p += 256 * 4;                 // 1 KB barriers

  // 1) all conversions + barrier zeroing
  {
    int c0 = V_ * H_ / 4, c1 = N_ * CIN / 4, c2 = H_ * CIN / 4;
    int c3 = G4 * H_ / 4, c4 = G4 * H_ / 4;
    int tot = c0 + c1 + c2 + c3 + c4;
    cvt_all<<<(tot + 255) / 256, 256, 0, stream>>>(
        W_out, Wout_b, c0, context, Ctxin_b, c1, W_merge, Wmrg_b, c2,
        W_ih, Wih_b, c3, W_hh, Whh_b, c4, bar);
  }

  // 2) fused merge + x_proj + 8 LSTM steps
  decoder_core<<<dim3(H_ / 32, N_ / 32), 256, 0, stream>>>(
      Ctxin_b, Wmrg_b, b_merge, Wih_b, Whh_b, b_ih, b_hh, Ctx_b, Hall, bar);

  // 3) logits
  gemm_logits<<<dim3(4000), 256, 0, stream>>>(Hall, Wout_b, b_out, out);
}